// Round 2
// 660.747 us; speedup vs baseline: 1.1158x; 1.1158x over previous
//
#include <hip/hip_runtime.h>

#define NROWS 4096
#define DIM   128
#define SCOLS 32768

typedef short bf16x8 __attribute__((ext_vector_type(8)));
typedef float f32x4  __attribute__((ext_vector_type(4)));

__device__ __forceinline__ unsigned short f2bf(float f) {
    // round-to-nearest-even fp32 -> bf16 (inputs finite randn)
    unsigned int u = __builtin_bit_cast(unsigned int, f);
    u += 0x7fffu + ((u >> 16) & 1u);
    return (unsigned short)(u >> 16);
}

// ---------------------------------------------------------------------------
// prep: ONE-SHOT gather + fp32->bf16 convert into workspace (vs per-tile
// re-conversion: 537M -> 4.7M conversions). Layout is PRE-SWIZZLED:
//   ws[r][chunk c stored at slot c ^ (r&15)]   (16B chunks, 16 per 128-elem row)
// so the gemm can global_load_lds LINEARLY (rule #21: swizzle baked into the
// global source) and ds_read_b128 with the same XOR on the read side.
// Also: bias gather -> bias_ws, and the ids float tail of the output.
// ---------------------------------------------------------------------------
#define WCHUNKS (SCOLS * 16)   // 524288
#define XCHUNKS (NROWS * 16)   // 65536

__global__ __launch_bounds__(256) void prep_kernel(
    const float* __restrict__ x, const float* __restrict__ weight,
    const float* __restrict__ bias, const int* __restrict__ ids,
    float* __restrict__ out, unsigned short* __restrict__ w_ws,
    unsigned short* __restrict__ x_ws, float* __restrict__ bias_ws)
{
    int gid = blockIdx.x * 256 + threadIdx.x;
    if (gid < WCHUNKS) {
        int r = gid >> 4, c = gid & 15;          // 16 lanes share one row r
        int id = ids[r];
        const float4* src = (const float4*)(weight + (size_t)id * DIM);
        float4 v0 = src[2 * c], v1 = src[2 * c + 1];   // 32B contiguous / lane
        union { unsigned short u[8]; uint4 q; } b;
        b.u[0] = f2bf(v0.x); b.u[1] = f2bf(v0.y); b.u[2] = f2bf(v0.z); b.u[3] = f2bf(v0.w);
        b.u[4] = f2bf(v1.x); b.u[5] = f2bf(v1.y); b.u[6] = f2bf(v1.z); b.u[7] = f2bf(v1.w);
        *(uint4*)&w_ws[(size_t)r * DIM + (size_t)((c ^ (r & 15)) * 8)] = b.q;
    } else if (gid < WCHUNKS + XCHUNKS) {
        int g = gid - WCHUNKS;
        int r = g >> 4, c = g & 15;
        const float4* src = (const float4*)(x + (size_t)r * DIM);
        float4 v0 = src[2 * c], v1 = src[2 * c + 1];
        union { unsigned short u[8]; uint4 q; } b;
        b.u[0] = f2bf(v0.x); b.u[1] = f2bf(v0.y); b.u[2] = f2bf(v0.z); b.u[3] = f2bf(v0.w);
        b.u[4] = f2bf(v1.x); b.u[5] = f2bf(v1.y); b.u[6] = f2bf(v1.z); b.u[7] = f2bf(v1.w);
        *(uint4*)&x_ws[(size_t)r * DIM + (size_t)((c ^ (r & 15)) * 8)] = b.q;
    } else {
        int g = gid - (WCHUNKS + XCHUNKS);
        if (g < SCOLS) {
            int id = ids[g];
            bias_ws[g] = bias[id];
            out[(size_t)NROWS * SCOLS + g] = (float)id;   // ids < 2^24 -> exact
        }
    }
}

// ---------------------------------------------------------------------------
// gemm: 128x128 tile, K=128 resident. Staging = pure global_load_lds width-16
// (zero VALU, zero ds_write). MFMA operands SWAPPED vs previous version:
// mfma(w_frag, x_frag) puts D-row (= quad*4+reg, register-contiguous) on the
// s axis -> each f32x4 is 4 consecutive output columns -> f32x4 NT stores.
// ---------------------------------------------------------------------------
__global__ __launch_bounds__(256, 2) void lsh_gemm2(
    const unsigned short* __restrict__ w_ws,
    const unsigned short* __restrict__ x_ws,
    const float* __restrict__ bias_ws,
    float* __restrict__ out)
{
    __shared__ unsigned short lds_w[128 * 128];   // 32 KB (swizzled content)
    __shared__ unsigned short lds_x[128 * 128];   // 32 KB

    const int t    = threadIdx.x;
    const int s0   = blockIdx.x * 128;   // sample (column) tile
    const int n0   = blockIdx.y * 128;   // x-row tile
    const int lane = t & 63;
    const int wave = t >> 6;

    const char* wsrc = (const char*)(w_ws + (size_t)s0 * DIM);
    const char* xsrc = (const char*)(x_ws + (size_t)n0 * DIM);

    // 32 KB per tile = 8 x 1KB chunks per wave; source already swizzled so
    // LDS dest is linear (wave-uniform base + lane*16).
    #pragma unroll
    for (int j = 0; j < 8; ++j) {
        int boff = wave * 8192 + j * 1024;   // bytes
        int goff = boff + lane * 16;
        __builtin_amdgcn_global_load_lds(
            (const __attribute__((address_space(1))) void*)(wsrc + goff),
            (__attribute__((address_space(3))) void*)((char*)lds_w + boff),
            16, 0, 0);
        __builtin_amdgcn_global_load_lds(
            (const __attribute__((address_space(1))) void*)(xsrc + goff),
            (__attribute__((address_space(3))) void*)((char*)lds_x + boff),
            16, 0, 0);
    }
    __syncthreads();

    const int lrow = lane & 15;          // A/B operand: row = lane&15
    const int quad = lane >> 4;          // k = quad*8 + j
    const int wn   = (wave & 1) * 64;    // wave's 64-row sub-tile (n)
    const int wsc  = (wave >> 1) * 64;   // wave's 64-col sub-tile (s)

    f32x4 acc[4][4];
    #pragma unroll
    for (int a = 0; a < 4; ++a)
        #pragma unroll
        for (int b = 0; b < 4; ++b)
            acc[a][b] = (f32x4){0.f, 0.f, 0.f, 0.f};

    #pragma unroll
    for (int kk = 0; kk < 4; ++kk) {
        bf16x8 aw[4], bx[4];
        int cb = kk * 4 + quad;          // 16B chunk index of this lane's k-slice
        #pragma unroll
        for (int i = 0; i < 4; ++i) {
            int rw = wsc + i * 16 + lrow;   // s rows   (rw & 15 == lrow)
            int rn = wn  + i * 16 + lrow;   // n rows
            aw[i] = *(const bf16x8*)&lds_w[rw * 128 + ((cb ^ lrow) * 8)];
            bx[i] = *(const bf16x8*)&lds_x[rn * 128 + ((cb ^ lrow) * 8)];
        }
        #pragma unroll
        for (int a = 0; a < 4; ++a)
            #pragma unroll
            for (int b = 0; b < 4; ++b)
                acc[a][b] = __builtin_amdgcn_mfma_f32_16x16x32_bf16(
                    aw[a], bx[b], acc[a][b], 0, 0, 0);
    }

    // D layout: row(= s) = quad*4 + reg (contiguous in reg!), col(= n) = lane&15.
    // One f32x4 -> one 16B NT store; 4 quads per lane&15-group fill 64B per n row.
    #pragma unroll
    for (int a = 0; a < 4; ++a) {
        int sL = wsc + a * 16 + quad * 4;
        f32x4 b4 = *(const f32x4*)&bias_ws[s0 + sL];   // 16B-aligned
        #pragma unroll
        for (int b = 0; b < 4; ++b) {
            int n = n0 + wn + b * 16 + lrow;
            f32x4 v = acc[a][b] + b4;
            // streaming output, never re-read: keep it out of L2 so the
            // 9MB bf16 working set stays resident
            __builtin_nontemporal_store(v, (f32x4*)&out[(size_t)n * SCOLS + (s0 + sL)]);
        }
    }
}

// ---------------------------------------------------------------------------
// fallback (workspace too small): previous fused-conversion kernel, verbatim.
// ---------------------------------------------------------------------------
__global__ __launch_bounds__(256, 2) void lsh_gemm(
    const float* __restrict__ x,
    const float* __restrict__ weight,
    const float* __restrict__ bias,
    const int*   __restrict__ ids,
    float*       __restrict__ out)
{
    __shared__ unsigned short lds_x[128 * 128];
    __shared__ unsigned short lds_w[128 * 128];

    const int t  = threadIdx.x;
    const int s0 = blockIdx.x * 128;
    const int n0 = blockIdx.y * 128;

    #pragma unroll
    for (int i = 0; i < 16; ++i) {
        int f   = t + i * 256;
        int row = f >> 5;
        int c4  = f & 31;
        float4 v = ((const float4*)(x + (size_t)(n0 + row) * DIM))[c4];
        ushort4 b;
        b.x = f2bf(v.x); b.y = f2bf(v.y); b.z = f2bf(v.z); b.w = f2bf(v.w);
        int sw = (c4 >> 1) ^ (row & 15);
        *(ushort4*)&lds_x[row * 128 + sw * 8 + (c4 & 1) * 4] = b;
    }
    #pragma unroll
    for (int i = 0; i < 16; ++i) {
        int f   = t + i * 256;
        int row = f >> 5;
        int c4  = f & 31;
        int id  = ids[s0 + row];
        float4 v = ((const float4*)(weight + (size_t)id * DIM))[c4];
        ushort4 b;
        b.x = f2bf(v.x); b.y = f2bf(v.y); b.z = f2bf(v.z); b.w = f2bf(v.w);
        int sw = (c4 >> 1) ^ (row & 15);
        *(ushort4*)&lds_w[row * 128 + sw * 8 + (c4 & 1) * 4] = b;
    }
    __syncthreads();

    const int lane = t & 63;
    const int wave = t >> 6;
    const int lrow = lane & 15;
    const int quad = lane >> 4;
    const int wm   = (wave & 1) * 64;
    const int wsc  = (wave >> 1) * 64;

    f32x4 acc[4][4];
    #pragma unroll
    for (int a = 0; a < 4; ++a)
        #pragma unroll
        for (int b = 0; b < 4; ++b)
            acc[a][b] = (f32x4){0.f, 0.f, 0.f, 0.f};

    #pragma unroll
    for (int kk = 0; kk < 4; ++kk) {
        bf16x8 af[4], bv[4];
        int cbase = kk * 4 + quad;
        #pragma unroll
        for (int i = 0; i < 4; ++i) {
            int rowa = wm  + i * 16 + lrow;
            int rowb = wsc + i * 16 + lrow;
            af[i] = *(const bf16x8*)&lds_x[rowa * 128 + (cbase ^ lrow) * 8];
            bv[i] = *(const bf16x8*)&lds_w[rowb * 128 + (cbase ^ lrow) * 8];
        }
        #pragma unroll
        for (int tm = 0; tm < 4; ++tm)
            #pragma unroll
            for (int ts = 0; ts < 4; ++ts)
                acc[tm][ts] = __builtin_amdgcn_mfma_f32_16x16x32_bf16(
                    af[tm], bv[ts], acc[tm][ts], 0, 0, 0);
    }

    #pragma unroll
    for (int ts = 0; ts < 4; ++ts) {
        int colL = wsc + ts * 16 + lrow;
        int col  = s0 + colL;
        float bvps = bias[ids[s0 + colL]];
        #pragma unroll
        for (int tm = 0; tm < 4; ++tm) {
            int rowbase = n0 + wm + tm * 16 + quad * 4;
            #pragma unroll
            for (int r = 0; r < 4; ++r)
                out[(size_t)(rowbase + r) * SCOLS + col] = acc[tm][ts][r] + bvps;
        }
    }
}

__global__ void ids_out_kernel(const int* __restrict__ ids, float* __restrict__ out)
{
    int i = blockIdx.x * 256 + threadIdx.x;
    if (i < SCOLS)
        out[(size_t)NROWS * SCOLS + i] = (float)ids[i];
}

extern "C" void kernel_launch(void* const* d_in, const int* in_sizes, int n_in,
                              void* d_out, int out_size, void* d_ws, size_t ws_size,
                              hipStream_t stream) {
    const float* x      = (const float*)d_in[0];
    const float* weight = (const float*)d_in[1];
    const float* bias   = (const float*)d_in[2];
    const int*   ids    = (const int*)d_in[3];
    float*       out    = (float*)d_out;

    const size_t W_BYTES = (size_t)SCOLS * DIM * 2;   // 8 MB   bf16 gathered W
    const size_t X_BYTES = (size_t)NROWS * DIM * 2;   // 1 MB   bf16 x
    const size_t B_BYTES = (size_t)SCOLS * 4;         // 128 KB gathered bias

    if (ws_size >= W_BYTES + X_BYTES + B_BYTES) {
        unsigned short* w_ws   = (unsigned short*)d_ws;
        unsigned short* x_ws   = (unsigned short*)((char*)d_ws + W_BYTES);
        float*          bias_ws = (float*)((char*)d_ws + W_BYTES + X_BYTES);

        const int prep_blocks = (WCHUNKS + XCHUNKS + SCOLS) / 256;   // 2432 exact
        hipLaunchKernelGGL(prep_kernel, dim3(prep_blocks), dim3(256), 0, stream,
                           x, weight, bias, ids, out, w_ws, x_ws, bias_ws);
        hipLaunchKernelGGL(lsh_gemm2, dim3(SCOLS / 128, NROWS / 128), dim3(256), 0, stream,
                           w_ws, x_ws, bias_ws, out);
    } else {
        hipLaunchKernelGGL(lsh_gemm, dim3(SCOLS / 128, NROWS / 128), dim3(256), 0, stream,
                           x, weight, bias, ids, out);
        hipLaunchKernelGGL(ids_out_kernel, dim3(SCOLS / 256), dim3(256), 0, stream,
                           ids, out);
    }
}